// Round 7
// baseline (1493.688 us; speedup 1.0000x reference)
//
#include <hip/hip_runtime.h>

// Problem constants
constexpr int N  = 50000;    // nodes
constexpr int E  = 1600000;  // edges
constexpr int CH = 128;      // channels

// Bucketed build parameters
constexpr int BSZ  = 128;                  // nodes per bucket
constexpr int NB   = (N + BSZ - 1) / BSZ;  // 391 buckets
constexpr int PBLK = 256;                  // partition blocks
constexpr int EPB  = E / PBLK;             // 6250 edges per partition block

// Workspace layout (bytes, 256-aligned)
constexpr size_t H_OFF     = 0;                        // h bf16 [N*CH]
constexpr size_t H_SZ      = (size_t)N * CH * 2;       // 12,800,000
constexpr size_t WBF_OFF   = H_OFF + H_SZ;             // W bf16 [CH*CH]
constexpr size_t WBF_SZ    = (size_t)CH * CH * 2;      // 32,768
constexpr size_t PAIRS_OFF = WBF_OFF + WBF_SZ;         // bucket-sorted (dst,src) [E] int2
constexpr size_t PAIRS_SZ  = (size_t)E * 8;            // 12,800,000
constexpr size_t CNT_OFF   = PAIRS_OFF + PAIRS_SZ;     // counts [NB][PBLK]
constexpr size_t CNT_SZ    = (size_t)NB * PBLK * 4;    // 400,384
constexpr size_t BASE_OFF  = CNT_OFF + CNT_SZ;         // bucket bases [NB+1]
constexpr size_t BASE_SZ   = 2048;
constexpr size_t BTOT_OFF  = BASE_OFF + BASE_SZ;       // bucket totals [NB]
constexpr size_t BTOT_SZ   = 2048;
constexpr size_t REQUIRED  = BTOT_OFF + BTOT_SZ;       // ~26.0 MB
constexpr size_t FB_REQUIRED = PAIRS_OFF;              // fallback: h + wbf only

// float -> bf16 round-to-nearest-even (finite inputs)
static __device__ __forceinline__ ushort f2bf(float f) {
    unsigned u = __float_as_uint(f);
    return (ushort)((u + 0x7fffu + ((u >> 16) & 1u)) >> 16);
}
static __device__ __forceinline__ float bf_lo(unsigned u) { return __uint_as_float(u << 16); }
static __device__ __forceinline__ float bf_hi(unsigned u) { return __uint_as_float(u & 0xffff0000u); }

typedef __attribute__((ext_vector_type(8))) short bf16x8;
typedef __attribute__((ext_vector_type(4))) float f32x4;

// ---------------- W fp32 -> bf16 (fallback path only) ----------------
__global__ void convert_w(const float* __restrict__ W, ushort* __restrict__ wbf) {
    int i = blockIdx.x * 256 + threadIdx.x;
    wbf[i] = f2bf(W[i]);
}

// ---------------- GEMM via MFMA: h = bf16(x @ W^T + b) ----------------
// Block = 4 waves, 16 rows x 128 cols. Verified layouts (m89/m91):
// A[m=lane&15][k=q*8+j], B[n=lane&15][k=q*8+j], D col=lane&15,row=q*4+reg.
__global__ __launch_bounds__(256) void gemm_mfma(const float* __restrict__ x,
                                                 const ushort* __restrict__ wbf,
                                                 const float* __restrict__ bias,
                                                 ushort* __restrict__ h) {
    const int tid  = threadIdx.x;
    const int m    = tid & 15;
    const int q    = (tid >> 4) & 3;
    const int wave = tid >> 6;
    const int r0   = blockIdx.x * 16;
    const int c0   = wave * 32;

    const float*  xrow = x + (size_t)(r0 + m) * CH + q * 8;
    const ushort* w0   = wbf + (size_t)(c0 + m) * CH + q * 8;
    const ushort* w1   = w0 + 16 * CH;

    f32x4 acc0 = {0.f, 0.f, 0.f, 0.f};
    f32x4 acc1 = {0.f, 0.f, 0.f, 0.f};

#pragma unroll
    for (int kc = 0; kc < CH; kc += 32) {
        float4 xa = *(const float4*)(xrow + kc);
        float4 xb = *(const float4*)(xrow + kc + 4);
        bf16x8 a;
        a[0] = (short)f2bf(xa.x); a[1] = (short)f2bf(xa.y);
        a[2] = (short)f2bf(xa.z); a[3] = (short)f2bf(xa.w);
        a[4] = (short)f2bf(xb.x); a[5] = (short)f2bf(xb.y);
        a[6] = (short)f2bf(xb.z); a[7] = (short)f2bf(xb.w);
        bf16x8 b0 = *(const bf16x8*)(w0 + kc);
        bf16x8 b1 = *(const bf16x8*)(w1 + kc);
        acc0 = __builtin_amdgcn_mfma_f32_16x16x32_bf16(a, b0, acc0, 0, 0, 0);
        acc1 = __builtin_amdgcn_mfma_f32_16x16x32_bf16(a, b1, acc1, 0, 0, 0);
    }

    const int col0 = c0 + m;
    const float bb0 = bias[col0];
    const float bb1 = bias[col0 + 16];
#pragma unroll
    for (int r = 0; r < 4; r++) {
        size_t row = (size_t)(r0 + q * 4 + r) * CH;
        h[row + col0]      = f2bf(acc0[r] + bb0);
        h[row + col0 + 16] = f2bf(acc1[r] + bb1);
    }
}

// ---------------- pass 1a: per-block bucket histogram (+ fused W convert) ----------------
__global__ __launch_bounds__(256) void p1_count(const int* __restrict__ ei,
                                                int* __restrict__ counts,
                                                const float* __restrict__ W,
                                                ushort* __restrict__ wbf) {
    __shared__ int cnt[NB];
    const int t = threadIdx.x, k = blockIdx.x;
    if (k >= PBLK) {                 // 64 extra blocks: convert W to bf16
        int i = (k - PBLK) * 256 + t;
        wbf[i] = f2bf(W[i]);
        return;
    }
    for (int j = t; j < NB; j += 256) cnt[j] = 0;
    __syncthreads();
    const int* dp = ei + k * EPB;
    for (int i = t; i < EPB; i += 256) atomicAdd(&cnt[dp[i] >> 7], 1);
    __syncthreads();
    for (int j = t; j < NB; j += 256) counts[j * PBLK + k] = cnt[j];  // bucket-major
}

// ---------------- hierarchical scan, level A: per-bucket row scan ----------------
__global__ __launch_bounds__(256) void scanA(int* __restrict__ counts,
                                             int* __restrict__ btot) {
    __shared__ int s[256];
    const int b = blockIdx.x, t = threadIdx.x;
    int v = counts[b * PBLK + t];
    s[t] = v;
    __syncthreads();
    for (int o = 1; o < 256; o <<= 1) {
        int u = (t >= o) ? s[t - o] : 0;
        __syncthreads();
        s[t] += u;
        __syncthreads();
    }
    counts[b * PBLK + t] = s[t] - v;     // exclusive within bucket
    if (t == 255) btot[b] = s[t];
}

// ---------------- hierarchical scan, level B: bucket bases ----------------
__global__ __launch_bounds__(1024) void scanB(const int* __restrict__ btot,
                                              int* __restrict__ base) {
    __shared__ int s[1024];
    const int t = threadIdx.x;
    int v = (t < NB) ? btot[t] : 0;
    s[t] = v;
    __syncthreads();
    for (int o = 1; o < 1024; o <<= 1) {
        int u = (t >= o) ? s[t - o] : 0;
        __syncthreads();
        s[t] += u;
        __syncthreads();
    }
    if (t <= NB) base[t] = s[t] - v;     // base[NB] = E
}

// ---------------- pass 1b: scatter (dst,src) int2 into private slots ----------------
__global__ __launch_bounds__(256) void p1_write(const int* __restrict__ ei,
                                                const int* __restrict__ counts,
                                                const int* __restrict__ base,
                                                int2* __restrict__ pairs) {
    __shared__ int cur[NB];
    const int t = threadIdx.x, k = blockIdx.x;
    for (int j = t; j < NB; j += 256) cur[j] = base[j] + counts[j * PBLK + k];
    __syncthreads();
    const int* dp = ei + k * EPB;
    const int* sp = ei + E + k * EPB;
    for (int i = t; i < EPB; i += 256) {
        int d = dp[i], s = sp[i];
        int p = atomicAdd(&cur[d >> 7], 1);
        pairs[p] = make_int2(d, s);
    }
}

// ---------------- push aggregation: LDS fp32 accumulators per bucket ----------------
// One block per bucket: acc[128 nodes][128 ch] fp32 = 64 KB LDS (2 blocks/CU).
// 8 waves; each half-wave owns one edge per step, lane reads uint2 (4 bf16 ch)
// of h[src] and ds_add_f32's into acc[dst]. Bank-clean: lanes hit distinct
// channels. Epilogue: coalesced float4 store of the bucket's out rows.
__global__ __launch_bounds__(512) void agg_push(const ushort* __restrict__ h,
                                                const int2* __restrict__ pairs,
                                                const int* __restrict__ base,
                                                float* __restrict__ out) {
    __shared__ float acc[BSZ * CH];      // 65536 B
    const int b = blockIdx.x, t = threadIdx.x;

    float4 z = make_float4(0.f, 0.f, 0.f, 0.f);
    for (int i = t; i < BSZ * CH / 4; i += 512) ((float4*)acc)[i] = z;
    __syncthreads();

    const int lo = base[b], hi = base[b + 1];
    const int wave = t >> 6;
    const int lane = t & 63;
    const int half = lane >> 5;          // 0/1: which edge of the pair
    const int cl   = lane & 31;          // channel quad 0..31
    const ushort* hp = h + (size_t)cl * 4;

    int e = lo + wave * 2 + half;        // stride 16 covers [lo,hi) exactly once
    for (; e + 16 < hi; e += 32) {       // 2x unrolled: 2 gathers in flight
        int2 p0 = pairs[e];
        int2 p1 = pairs[e + 16];
        uint2 v0 = *(const uint2*)(hp + (size_t)p0.y * CH);
        uint2 v1 = *(const uint2*)(hp + (size_t)p1.y * CH);
        float* a0 = acc + (p0.x & (BSZ - 1)) * CH + cl * 4;
        float* a1 = acc + (p1.x & (BSZ - 1)) * CH + cl * 4;
        atomicAdd(a0 + 0, bf_lo(v0.x)); atomicAdd(a0 + 1, bf_hi(v0.x));
        atomicAdd(a0 + 2, bf_lo(v0.y)); atomicAdd(a0 + 3, bf_hi(v0.y));
        atomicAdd(a1 + 0, bf_lo(v1.x)); atomicAdd(a1 + 1, bf_hi(v1.x));
        atomicAdd(a1 + 2, bf_lo(v1.y)); atomicAdd(a1 + 3, bf_hi(v1.y));
    }
    for (; e < hi; e += 16) {
        int2 p = pairs[e];
        uint2 v = *(const uint2*)(hp + (size_t)p.y * CH);
        float* a = acc + (p.x & (BSZ - 1)) * CH + cl * 4;
        atomicAdd(a + 0, bf_lo(v.x)); atomicAdd(a + 1, bf_hi(v.x));
        atomicAdd(a + 2, bf_lo(v.y)); atomicAdd(a + 3, bf_hi(v.y));
    }
    __syncthreads();

    const int n0 = b * BSZ;
    const int nvalid = (N - n0 < BSZ) ? (N - n0) : BSZ;   // last bucket: 80
    float4* op = (float4*)(out + (size_t)n0 * CH);
    for (int i = t; i < nvalid * (CH / 4); i += 512) op[i] = ((float4*)acc)[i];
}

// ---------------- fallback: direct atomic scatter ----------------
__global__ void atomic_agg(const ushort* __restrict__ h, const int* __restrict__ ei,
                           float* __restrict__ out) {
    int tid = blockIdx.x * blockDim.x + threadIdx.x;
    int e  = tid >> 5;
    int cg = (tid & 31) * 4;
    if (e < E) {
        int d = ei[e];
        int s = ei[E + e];
        ushort4 v = *(const ushort4*)(h + (size_t)s * CH + cg);
        float* o = out + (size_t)d * CH + cg;
        atomicAdd(o + 0, __uint_as_float((unsigned)v.x << 16));
        atomicAdd(o + 1, __uint_as_float((unsigned)v.y << 16));
        atomicAdd(o + 2, __uint_as_float((unsigned)v.z << 16));
        atomicAdd(o + 3, __uint_as_float((unsigned)v.w << 16));
    }
}

extern "C" void kernel_launch(void* const* d_in, const int* in_sizes, int n_in,
                              void* d_out, int out_size, void* d_ws, size_t ws_size,
                              hipStream_t stream) {
    const float* x  = (const float*)d_in[0];
    const int*   ei = (const int*)d_in[1];   // [2][E] int32: row0=dst, row1=src
    const float* W  = (const float*)d_in[2];
    const float* b  = (const float*)d_in[3];
    float* out = (float*)d_out;

    char* ws = (char*)d_ws;
    ushort* h   = (ushort*)(ws + H_OFF);
    ushort* wbf = (ushort*)(ws + WBF_OFF);

    if (ws_size >= REQUIRED) {
        int2* pairs  = (int2*)(ws + PAIRS_OFF);
        int*  counts = (int*)(ws + CNT_OFF);
        int*  base   = (int*)(ws + BASE_OFF);
        int*  btot   = (int*)(ws + BTOT_OFF);

        p1_count<<<PBLK + 64, 256, 0, stream>>>(ei, counts, W, wbf);  // + W convert
        gemm_mfma<<<N / 16, 256, 0, stream>>>(x, wbf, b, h);
        scanA<<<NB, 256, 0, stream>>>(counts, btot);
        scanB<<<1, 1024, 0, stream>>>(btot, base);
        p1_write<<<PBLK, 256, 0, stream>>>(ei, counts, base, pairs);
        agg_push<<<NB, 512, 0, stream>>>(h, pairs, base, out);
    } else if (ws_size >= FB_REQUIRED) {
        convert_w<<<64, 256, 0, stream>>>(W, wbf);
        gemm_mfma<<<N / 16, 256, 0, stream>>>(x, wbf, b, h);
        hipMemsetAsync(out, 0, (size_t)out_size * sizeof(float), stream);
        int total = E * 32;
        atomic_agg<<<(total + 255) / 256, 256, 0, stream>>>(h, ei, out);
    }
}

// Round 8
// 192.999 us; speedup vs baseline: 7.7394x; 7.7394x over previous
//
#include <hip/hip_runtime.h>

// Problem constants
constexpr int N  = 50000;    // nodes
constexpr int E  = 1600000;  // edges
constexpr int CH = 128;      // channels

// Bucketed build parameters
constexpr int BSZ  = 128;                  // nodes per bucket
constexpr int NB   = (N + BSZ - 1) / BSZ;  // 391 buckets
constexpr int PBLK = 256;                  // partition blocks
constexpr int EPB  = E / PBLK;             // 6250 edges per partition block
constexpr int GEMM_BLOCKS = N / 16;        // 3125
constexpr int CHUNK = 4608;                // edges per LDS chunk (mean bucket=4096, +8 sigma)

// Workspace layout (bytes, 256-aligned)
constexpr size_t H_OFF     = 0;                        // h bf16 [N*CH]
constexpr size_t H_SZ      = (size_t)N * CH * 2;       // 12,800,000
constexpr size_t PAIRS_OFF = H_OFF + H_SZ;             // packed (dstLoc<<16|src) [E] u32
constexpr size_t PAIRS_SZ  = (size_t)E * 4;            // 6,400,000
constexpr size_t CNT_OFF   = PAIRS_OFF + PAIRS_SZ;     // counts [NB][PBLK]
constexpr size_t CNT_SZ    = (size_t)NB * PBLK * 4;    // 400,384
constexpr size_t BASE_OFF  = CNT_OFF + CNT_SZ;         // bucket bases [NB+1]
constexpr size_t BASE_SZ   = 2048;
constexpr size_t BTOT_OFF  = BASE_OFF + BASE_SZ;       // bucket totals [NB]
constexpr size_t BTOT_SZ   = 2048;
constexpr size_t REQUIRED  = BTOT_OFF + BTOT_SZ;       // ~19.6 MB
constexpr size_t FB_REQUIRED = H_SZ;                   // fallback: h only

// float -> bf16 round-to-nearest-even (finite inputs)
static __device__ __forceinline__ ushort f2bf(float f) {
    unsigned u = __float_as_uint(f);
    return (ushort)((u + 0x7fffu + ((u >> 16) & 1u)) >> 16);
}
static __device__ __forceinline__ float bf_lo(unsigned u) { return __uint_as_float(u << 16); }
static __device__ __forceinline__ float bf_hi(unsigned u) { return __uint_as_float(u & 0xffff0000u); }

typedef __attribute__((ext_vector_type(8))) short bf16x8;
typedef __attribute__((ext_vector_type(4))) float f32x4;

// ---------------- fused: GEMM (blocks < GEMM_BLOCKS) | bucket histogram ----------------
// GEMM: block = 4 waves, 16 rows x 128 cols, mfma_f32_16x16x32_bf16.
// Verified layouts (m89/m91): A[m=lane&15][k=q*8+j], B[n=lane&15][k=q*8+j],
// D col=lane&15, row=q*4+reg. W converted fp32->bf16 in-register (W is 64 KB,
// L2-resident across blocks). p1_count: per-partition-block bucket histogram
// with native int LDS atomics (fp LDS atomics are CAS-loop poison - see R7).
__global__ __launch_bounds__(256) void gemm_and_count(const float* __restrict__ x,
                                                      const float* __restrict__ W,
                                                      const float* __restrict__ bias,
                                                      ushort* __restrict__ h,
                                                      const int* __restrict__ ei,
                                                      int* __restrict__ counts) {
    __shared__ int cnt[NB];
    const int bid = blockIdx.x;
    const int tid = threadIdx.x;

    if (bid >= GEMM_BLOCKS) {
        // ---- p1_count role ----
        const int k = bid - GEMM_BLOCKS;
        for (int j = tid; j < NB; j += 256) cnt[j] = 0;
        __syncthreads();
        const int* dp = ei + k * EPB;
        for (int i = tid; i < EPB; i += 256) atomicAdd(&cnt[dp[i] >> 7], 1);
        __syncthreads();
        for (int j = tid; j < NB; j += 256) counts[j * PBLK + k] = cnt[j];
        return;
    }

    // ---- GEMM role ----
    const int m    = tid & 15;
    const int q    = (tid >> 4) & 3;
    const int wave = tid >> 6;
    const int r0   = bid * 16;
    const int c0   = wave * 32;

    const float* xrow = x + (size_t)(r0 + m) * CH + q * 8;
    const float* wr0  = W + (size_t)(c0 + m) * CH + q * 8;        // B rows c0+m
    const float* wr1  = wr0 + 16 * CH;                            // and c0+16+m

    f32x4 acc0 = {0.f, 0.f, 0.f, 0.f};
    f32x4 acc1 = {0.f, 0.f, 0.f, 0.f};

#pragma unroll
    for (int kc = 0; kc < CH; kc += 32) {
        float4 xa = *(const float4*)(xrow + kc);
        float4 xb = *(const float4*)(xrow + kc + 4);
        float4 wa0 = *(const float4*)(wr0 + kc);
        float4 wb0 = *(const float4*)(wr0 + kc + 4);
        float4 wa1 = *(const float4*)(wr1 + kc);
        float4 wb1 = *(const float4*)(wr1 + kc + 4);
        bf16x8 a, b0, b1;
        a[0] = (short)f2bf(xa.x); a[1] = (short)f2bf(xa.y);
        a[2] = (short)f2bf(xa.z); a[3] = (short)f2bf(xa.w);
        a[4] = (short)f2bf(xb.x); a[5] = (short)f2bf(xb.y);
        a[6] = (short)f2bf(xb.z); a[7] = (short)f2bf(xb.w);
        b0[0] = (short)f2bf(wa0.x); b0[1] = (short)f2bf(wa0.y);
        b0[2] = (short)f2bf(wa0.z); b0[3] = (short)f2bf(wa0.w);
        b0[4] = (short)f2bf(wb0.x); b0[5] = (short)f2bf(wb0.y);
        b0[6] = (short)f2bf(wb0.z); b0[7] = (short)f2bf(wb0.w);
        b1[0] = (short)f2bf(wa1.x); b1[1] = (short)f2bf(wa1.y);
        b1[2] = (short)f2bf(wa1.z); b1[3] = (short)f2bf(wa1.w);
        b1[4] = (short)f2bf(wb1.x); b1[5] = (short)f2bf(wb1.y);
        b1[6] = (short)f2bf(wb1.z); b1[7] = (short)f2bf(wb1.w);
        acc0 = __builtin_amdgcn_mfma_f32_16x16x32_bf16(a, b0, acc0, 0, 0, 0);
        acc1 = __builtin_amdgcn_mfma_f32_16x16x32_bf16(a, b1, acc1, 0, 0, 0);
    }

    const int col0 = c0 + m;
    const float bb0 = bias[col0];
    const float bb1 = bias[col0 + 16];
#pragma unroll
    for (int r = 0; r < 4; r++) {
        size_t row = (size_t)(r0 + q * 4 + r) * CH;
        h[row + col0]      = f2bf(acc0[r] + bb0);
        h[row + col0 + 16] = f2bf(acc1[r] + bb1);
    }
}

// ---------------- hierarchical scan, level A: per-bucket row scan ----------------
__global__ __launch_bounds__(256) void scanA(int* __restrict__ counts,
                                             int* __restrict__ btot) {
    __shared__ int s[256];
    const int b = blockIdx.x, t = threadIdx.x;
    int v = counts[b * PBLK + t];
    s[t] = v;
    __syncthreads();
    for (int o = 1; o < 256; o <<= 1) {
        int u = (t >= o) ? s[t - o] : 0;
        __syncthreads();
        s[t] += u;
        __syncthreads();
    }
    counts[b * PBLK + t] = s[t] - v;     // exclusive within bucket
    if (t == 255) btot[b] = s[t];
}

// ---------------- hierarchical scan, level B: bucket bases ----------------
__global__ __launch_bounds__(1024) void scanB(const int* __restrict__ btot,
                                              int* __restrict__ base) {
    __shared__ int s[1024];
    const int t = threadIdx.x;
    int v = (t < NB) ? btot[t] : 0;
    s[t] = v;
    __syncthreads();
    for (int o = 1; o < 1024; o <<= 1) {
        int u = (t >= o) ? s[t - o] : 0;
        __syncthreads();
        s[t] += u;
        __syncthreads();
    }
    if (t <= NB) base[t] = s[t] - v;     // base[NB] = E
}

// ---------------- pass 1b: scatter packed (dstLoc<<16|src) into private slots ----------------
__global__ __launch_bounds__(256) void p1_write(const int* __restrict__ ei,
                                                const int* __restrict__ counts,
                                                const int* __restrict__ base,
                                                unsigned* __restrict__ pairs) {
    __shared__ int cur[NB];
    const int t = threadIdx.x, k = blockIdx.x;
    for (int j = t; j < NB; j += 256) cur[j] = base[j] + counts[j * PBLK + k];
    __syncthreads();
    const int* dp = ei + k * EPB;
    const int* sp = ei + E + k * EPB;
    for (int i = t; i < EPB; i += 256) {
        int d = dp[i], s = sp[i];
        int p = atomicAdd(&cur[d >> 7], 1);
        pairs[p] = ((unsigned)(d & (BSZ - 1)) << 16) | (unsigned)s;
    }
}

// ---------------- fused local-CSR build + pull aggregation ----------------
// One block (8 waves) per bucket. Per CHUNK of the bucket's packed pairs:
// stage to LDS raw[], int-atomic hist, ladder scan, scatter src16 into srt[]
// (local CSR lives entirely in LDS), then each wave pull-aggregates its 16
// nodes from srt with register accumulators (R6 gather structure: half-wave
// per edge, lane = 4 channels, 4x unrolled uint2 gathers). No global CSR,
// no fp atomics anywhere.
__global__ __launch_bounds__(512) void agg_fused(const ushort* __restrict__ h,
                                                 const unsigned* __restrict__ pairs,
                                                 const int* __restrict__ base,
                                                 float* __restrict__ out) {
    __shared__ unsigned raw[CHUNK];      // 18432 B
    __shared__ ushort   srt[CHUNK];      //  9216 B
    __shared__ int hist[BSZ], offs[BSZ], cur[BSZ];
    const int b = blockIdx.x, t = threadIdx.x;
    const int lo = base[b], hi = base[b + 1];
    const int wave = t >> 6;
    const int lane = t & 63;
    const int half = lane >> 5;          // 0/1: which edge of a pair of edges
    const int cl   = lane & 31;          // channel quad 0..31
    const ushort* hp = h + (size_t)cl * 4;

    float acc[16][4];
#pragma unroll
    for (int j = 0; j < 16; j++) {
        acc[j][0] = 0.f; acc[j][1] = 0.f; acc[j][2] = 0.f; acc[j][3] = 0.f;
    }

    for (int c0 = lo; c0 < hi; c0 += CHUNK) {
        const int cnt = min(CHUNK, hi - c0);
        __syncthreads();                          // protect LDS reuse across chunks
        for (int i = t; i < cnt; i += 512) raw[i] = pairs[c0 + i];
        if (t < BSZ) hist[t] = 0;
        __syncthreads();
        for (int i = t; i < cnt; i += 512) atomicAdd(&hist[raw[i] >> 16], 1);
        __syncthreads();
        // exclusive scan of hist[128] (ladder in offs)
        int v = (t < BSZ) ? hist[t] : 0;
        if (t < BSZ) offs[t] = v;
        __syncthreads();
        for (int o = 1; o < BSZ; o <<= 1) {
            int u = 0;
            if (t < BSZ && t >= o) u = offs[t - o];
            __syncthreads();
            if (t < BSZ) offs[t] += u;
            __syncthreads();
        }
        if (t < BSZ) { int excl = offs[t] - v; offs[t] = excl; cur[t] = excl; }
        __syncthreads();
        for (int i = t; i < cnt; i += 512) {
            unsigned w = raw[i];
            int p = atomicAdd(&cur[w >> 16], 1);
            srt[p] = (ushort)(w & 0xffffu);
        }
        __syncthreads();
        // pull-aggregate this chunk: wave handles nodes [wave*16, wave*16+16)
#pragma unroll
        for (int j = 0; j < 16; j++) {
            const int nl = wave * 16 + j;
            const int st = offs[nl];
            const int c  = hist[nl];
            float a0 = acc[j][0], a1 = acc[j][1], a2 = acc[j][2], a3 = acc[j][3];
            int i = 0;
            for (; i + 8 <= c; i += 8) {
                const int e0 = st + i + half;
                int s0 = srt[e0];
                int s1 = srt[e0 + 2];
                int s2 = srt[e0 + 4];
                int s3 = srt[e0 + 6];
                uint2 v0 = *(const uint2*)(hp + (size_t)s0 * CH);
                uint2 v1 = *(const uint2*)(hp + (size_t)s1 * CH);
                uint2 v2 = *(const uint2*)(hp + (size_t)s2 * CH);
                uint2 v3 = *(const uint2*)(hp + (size_t)s3 * CH);
                a0 += bf_lo(v0.x); a1 += bf_hi(v0.x); a2 += bf_lo(v0.y); a3 += bf_hi(v0.y);
                a0 += bf_lo(v1.x); a1 += bf_hi(v1.x); a2 += bf_lo(v1.y); a3 += bf_hi(v1.y);
                a0 += bf_lo(v2.x); a1 += bf_hi(v2.x); a2 += bf_lo(v2.y); a3 += bf_hi(v2.y);
                a0 += bf_lo(v3.x); a1 += bf_hi(v3.x); a2 += bf_lo(v3.y); a3 += bf_hi(v3.y);
            }
            for (; i + 2 <= c; i += 2) {
                int s = srt[st + i + half];
                uint2 v2 = *(const uint2*)(hp + (size_t)s * CH);
                a0 += bf_lo(v2.x); a1 += bf_hi(v2.x); a2 += bf_lo(v2.y); a3 += bf_hi(v2.y);
            }
            if (i + half < c) {          // odd tail: half 0 only
                int s = srt[st + i + half];
                uint2 v2 = *(const uint2*)(hp + (size_t)s * CH);
                a0 += bf_lo(v2.x); a1 += bf_hi(v2.x); a2 += bf_lo(v2.y); a3 += bf_hi(v2.y);
            }
            acc[j][0] = a0; acc[j][1] = a1; acc[j][2] = a2; acc[j][3] = a3;
        }
    }

    // epilogue: reduce half-waves, coalesced float4 store
#pragma unroll
    for (int j = 0; j < 16; j++) {
        float a0 = acc[j][0] + __shfl_xor(acc[j][0], 32);
        float a1 = acc[j][1] + __shfl_xor(acc[j][1], 32);
        float a2 = acc[j][2] + __shfl_xor(acc[j][2], 32);
        float a3 = acc[j][3] + __shfl_xor(acc[j][3], 32);
        const int n = b * BSZ + wave * 16 + j;
        if (half == 0 && n < N) {
            *(float4*)(out + (size_t)n * CH + cl * 4) = make_float4(a0, a1, a2, a3);
        }
    }
}

// ---------------- fallback: direct atomic scatter (global fp32 atomics) ----------------
__global__ void atomic_agg(const ushort* __restrict__ h, const int* __restrict__ ei,
                           float* __restrict__ out) {
    int tid = blockIdx.x * blockDim.x + threadIdx.x;
    int e  = tid >> 5;
    int cg = (tid & 31) * 4;
    if (e < E) {
        int d = ei[e];
        int s = ei[E + e];
        ushort4 v = *(const ushort4*)(h + (size_t)s * CH + cg);
        float* o = out + (size_t)d * CH + cg;
        atomicAdd(o + 0, __uint_as_float((unsigned)v.x << 16));
        atomicAdd(o + 1, __uint_as_float((unsigned)v.y << 16));
        atomicAdd(o + 2, __uint_as_float((unsigned)v.z << 16));
        atomicAdd(o + 3, __uint_as_float((unsigned)v.w << 16));
    }
}

extern "C" void kernel_launch(void* const* d_in, const int* in_sizes, int n_in,
                              void* d_out, int out_size, void* d_ws, size_t ws_size,
                              hipStream_t stream) {
    const float* x  = (const float*)d_in[0];
    const int*   ei = (const int*)d_in[1];   // [2][E] int32: row0=dst, row1=src
    const float* W  = (const float*)d_in[2];
    const float* b  = (const float*)d_in[3];
    float* out = (float*)d_out;

    char* ws = (char*)d_ws;
    ushort* h = (ushort*)(ws + H_OFF);

    if (ws_size >= REQUIRED) {
        unsigned* pairs = (unsigned*)(ws + PAIRS_OFF);
        int* counts = (int*)(ws + CNT_OFF);
        int* base   = (int*)(ws + BASE_OFF);
        int* btot   = (int*)(ws + BTOT_OFF);

        gemm_and_count<<<GEMM_BLOCKS + PBLK, 256, 0, stream>>>(x, W, b, h, ei, counts);
        scanA<<<NB, 256, 0, stream>>>(counts, btot);
        scanB<<<1, 1024, 0, stream>>>(btot, base);
        p1_write<<<PBLK, 256, 0, stream>>>(ei, counts, base, pairs);
        agg_fused<<<NB, 512, 0, stream>>>(h, pairs, base, out);
    } else if (ws_size >= FB_REQUIRED) {
        gemm_and_count<<<GEMM_BLOCKS, 256, 0, stream>>>(x, W, b, h, ei, (int*)ws);
        hipMemsetAsync(out, 0, (size_t)out_size * sizeof(float), stream);
        int total = E * 32;
        atomic_agg<<<(total + 255) / 256, 256, 0, stream>>>(h, ei, out);
    }
}